// Round 7
// baseline (419.962 us; speedup 1.0000x reference)
//
#include <hip/hip_runtime.h>
#include <hip/hip_cooperative_groups.h>

namespace cg = cooperative_groups;

#define N_NODES 200000
#define C 256
#define VC 16
#define VD 3
#define VDIM (VC * VD)   // 48
#define M_MOTIFS 50000
#define M_PAD 50048      // padded rows: 50048 = 391 * 128
#define CAP 64           // per-motif slot capacity; Poisson(4) => P(count>64) ~ 1e-36

#define CB 512           // cooperative grid: 2 blocks/CU guaranteed co-resident
#define CT (CB * 256)    // 131072 threads
#define CW (CB * 4)      // 2048 waves
#define NTILES (2 * (M_PAD / 128))                // 782 (391 row-tiles x 2 col-halves)

#define NODE_BLOCKS ((N_NODES + 255) / 256)       // 782 (fallback path)
#define CVT_BLOCKS  ((C * C) / (256 * 4))         // 64
#define GATHER_BLOCKS (M_MOTIFS / 4)              // 12500

typedef __attribute__((ext_vector_type(8))) __bf16 bf16x8;
typedef __attribute__((ext_vector_type(4))) float f32x4;

__device__ __forceinline__ unsigned short f2bf(float x) {
  unsigned u = __builtin_bit_cast(unsigned, x);
  u += 0x7fffu + ((u >> 16) & 1u);   // RNE
  return (unsigned short)(u >> 16);
}

// async global->LDS, 16B per lane; LDS dest = wave-uniform base + lane*16
__device__ __forceinline__ void async_copy16(const void* g, void* l) {
  __builtin_amdgcn_global_load_lds(
      (const __attribute__((address_space(1))) unsigned int*)g,
      (__attribute__((address_space(3))) unsigned int*)l, 16, 0, 0);
}

// ---------------------------------------------------------------------------
// R3-verified gather body for ONE motif (k wave-uniform, idv = 16 slot ids in
// lanes 0..15 replicated).
// ---------------------------------------------------------------------------
__device__ __forceinline__ void gather_one(
    int m, int k, int idv, int lane, const float* __restrict__ s,
    const float* __restrict__ v, const int* __restrict__ nodelist,
    const float* __restrict__ Wv, const float* __restrict__ bv,
    unsigned short* __restrict__ s_motif, float* __restrict__ v_out) {
  if (k == 0) {                                    // ~1.8% of motifs
    ushort4 z; z.x = z.y = z.z = z.w = 0;
    ((ushort4*)(s_motif + (size_t)m * C))[lane] = z;
    if (lane < VDIM) v_out[(size_t)m * VDIM + lane] = bv[lane / 3];
    return;
  }
  int km1 = k - 1;
  int kc = min(k, CAP);

  // batch 0: slots 0..3 (clamped; duplicates are same-address L1 hits)
  int i0 = __shfl(idv, 0, 64);
  int i1 = __shfl(idv, min(1, km1), 64);
  int i2 = __shfl(idv, min(2, km1), 64);
  int i3 = __shfl(idv, min(3, km1), 64);
  float4 a0 = ((const float4*)(s + (size_t)i0 * C))[lane];
  float4 a1 = ((const float4*)(s + (size_t)i1 * C))[lane];
  float4 a2 = ((const float4*)(s + (size_t)i2 * C))[lane];
  float4 a3 = ((const float4*)(s + (size_t)i3 * C))[lane];
  float vb0 = 0.f, vb1 = 0.f, vb2 = 0.f, vb3 = 0.f;
  if (lane < VDIM) {
    vb0 = v[(size_t)i0 * VDIM + lane];
    vb1 = v[(size_t)i1 * VDIM + lane];
    vb2 = v[(size_t)i2 * VDIM + lane];
    vb3 = v[(size_t)i3 * VDIM + lane];
  }
  float4 acc = a0;
  float vacc = vb0;
  if (k > 1) { acc.x += a1.x; acc.y += a1.y; acc.z += a1.z; acc.w += a1.w; vacc += vb1; }
  if (k > 2) { acc.x += a2.x; acc.y += a2.y; acc.z += a2.z; acc.w += a2.w; vacc += vb2; }
  if (k > 3) { acc.x += a3.x; acc.y += a3.y; acc.z += a3.z; acc.w += a3.w; vacc += vb3; }

  // batch 1: slots 4..7 (37% of motifs)
  if (k > 4) {
    int i4 = __shfl(idv, min(4, km1), 64);
    int i5 = __shfl(idv, min(5, km1), 64);
    int i6 = __shfl(idv, min(6, km1), 64);
    int i7 = __shfl(idv, min(7, km1), 64);
    float4 b4 = ((const float4*)(s + (size_t)i4 * C))[lane];
    float4 b5 = ((const float4*)(s + (size_t)i5 * C))[lane];
    float4 b6 = ((const float4*)(s + (size_t)i6 * C))[lane];
    float4 b7 = ((const float4*)(s + (size_t)i7 * C))[lane];
    float w4 = 0.f, w5 = 0.f, w6 = 0.f, w7 = 0.f;
    if (lane < VDIM) {
      w4 = v[(size_t)i4 * VDIM + lane];
      w5 = v[(size_t)i5 * VDIM + lane];
      w6 = v[(size_t)i6 * VDIM + lane];
      w7 = v[(size_t)i7 * VDIM + lane];
    }
    acc.x += b4.x; acc.y += b4.y; acc.z += b4.z; acc.w += b4.w; vacc += w4;
    if (k > 5) { acc.x += b5.x; acc.y += b5.y; acc.z += b5.z; acc.w += b5.w; vacc += w5; }
    if (k > 6) { acc.x += b6.x; acc.y += b6.y; acc.z += b6.z; acc.w += b6.w; vacc += w6; }
    if (k > 7) { acc.x += b7.x; acc.y += b7.y; acc.z += b7.z; acc.w += b7.w; vacc += w7; }
  }

  // rare tail: slots 8.. (2% of motifs)
  if (k > 8) {
    int idv2 = nodelist[(size_t)m * CAP + lane];
    for (int j = 8; j < kc; ++j) {
      int ij = __shfl(idv2, j, 64);
      float4 a = ((const float4*)(s + (size_t)ij * C))[lane];
      acc.x += a.x; acc.y += a.y; acc.z += a.z; acc.w += a.w;
      if (lane < VDIM) vacc += v[(size_t)ij * VDIM + lane];
    }
  }

  float rc = 1.0f / (float)k;
  ushort4 o;
  o.x = f2bf(acc.x * rc); o.y = f2bf(acc.y * rc);
  o.z = f2bf(acc.z * rc); o.w = f2bf(acc.w * rc);
  ((ushort4*)(s_motif + (size_t)m * C))[lane] = o;

  float vm = vacc * rc;   // lane c*3+d holds vmean[c][d]
  if (lane < VDIM) {
    int oo = lane / 3, d = lane - oo * 3;
    float vo = bv[oo];
#pragma unroll
    for (int c2 = 0; c2 < VC; ++c2)
      vo += Wv[oo * VC + c2] * __shfl(vm, c2 * 3 + d, 64);
    v_out[(size_t)m * VDIM + lane] = vo;
  }
}

// ---------------------------------------------------------------------------
// Cooperative mega-kernel: {zero; fill+cvt; gather(prefetch); GEMM} with
// grid.sync between phases. Phase bodies are the R3-verified ones.
// ---------------------------------------------------------------------------
__global__ __launch_bounds__(256, 2) void mega_kernel(
    const float* __restrict__ s, const float* __restrict__ v,
    const int* __restrict__ seg, const float* __restrict__ Ws,
    const float* __restrict__ bs, const float* __restrict__ Wv,
    const float* __restrict__ bv, int* __restrict__ cnt,
    int* __restrict__ nodelist, unsigned short* __restrict__ Wsb,
    unsigned short* __restrict__ s_motif, float* __restrict__ s_out,
    float* __restrict__ v_out) {
  cg::grid_group gg = cg::this_grid();
  __shared__ unsigned short As[128 * 32];
  __shared__ unsigned short Bs[128 * 32];

  int tid = threadIdx.x;
  int gid = blockIdx.x * 256 + tid;

  // ---- phase 0: zero cnt (50000 < 131072: single pass) ----
  if (gid < M_MOTIFS) cnt[gid] = 0;
  gg.sync();

  // ---- phase 1: slot-fill + Ws -> bf16 ----
  for (int i = gid; i < N_NODES; i += CT) {
    int m = seg[i];
    int r = atomicAdd(&cnt[m], 1);
    if (r < CAP) nodelist[(size_t)m * CAP + r] = i;
  }
  if (gid < (C * C) / 4) {
    float4 w = ((const float4*)Ws)[gid];
    ushort4 o;
    o.x = f2bf(w.x); o.y = f2bf(w.y); o.z = f2bf(w.z); o.w = f2bf(w.w);
    ((ushort4*)Wsb)[gid] = o;
  }
  __threadfence();
  gg.sync();

  // ---- phase 2: gather, persistent waves with metadata prefetch ----
  {
    int lane = tid & 63;
    int m = gid >> 6;                    // global wave id, 0..2047
    int k = 0, idv = 0;
    if (m < M_MOTIFS) {
      k = cnt[m];
      idv = nodelist[(size_t)m * CAP + (lane & 15)];
    }
    while (m < M_MOTIFS) {
      int mn = m + CW;
      int kn = 0, idn = 0;
      if (mn < M_MOTIFS) {               // prefetch next motif's metadata
        kn = cnt[mn];
        idn = nodelist[(size_t)mn * CAP + (lane & 15)];
      }
      gather_one(m, k, idv, lane, s, v, nodelist, Wv, bv, s_motif, v_out);
      m = mn; k = kn; idv = idn;
    }
  }
  __threadfence();
  gg.sync();

  // ---- phase 3: tiled MFMA GEMM (R3 body), grid-stride over 782 tiles ----
  {
    int wave = tid >> 6, lane = tid & 63;
    int wm = (wave >> 1) * 64, wn = (wave & 1) * 64;
    int srow = lane >> 2;
    int kc = (lane & 3) * 8;
    int rl = lane & 15;
    int kq = (lane >> 4) * 8;
    int rq = (lane >> 4) * 4;

    for (int t = blockIdx.x; t < NTILES; t += CB) {
      int m0 = (t >> 1) * 128;
      int n0 = (t & 1) * 128;

      f32x4 acc[4][4] = {};
      const unsigned short* Ag = s_motif + (size_t)(m0 + wave * 32) * C;
      const unsigned short* Bg = Wsb + (size_t)(n0 + wave * 32) * C;
      unsigned short* Al = As + wave * 32 * 32;
      unsigned short* Bl = Bs + wave * 32 * 32;

      for (int k0 = 0; k0 < C; k0 += 32) {
        async_copy16(Ag + (size_t)srow * C + k0 + kc, Al);
        async_copy16(Ag + (size_t)(16 + srow) * C + k0 + kc, Al + 16 * 32);
        async_copy16(Bg + (size_t)srow * C + k0 + kc, Bl);
        async_copy16(Bg + (size_t)(16 + srow) * C + k0 + kc, Bl + 16 * 32);
        __syncthreads();

        bf16x8 af[4], bfr[4];
#pragma unroll
        for (int i = 0; i < 4; ++i)
          af[i] = *(const bf16x8*)&As[(size_t)(wm + i * 16 + rl) * 32 + kq];
#pragma unroll
        for (int j = 0; j < 4; ++j)
          bfr[j] = *(const bf16x8*)&Bs[(size_t)(wn + j * 16 + rl) * 32 + kq];
#pragma unroll
        for (int i = 0; i < 4; ++i)
#pragma unroll
          for (int j = 0; j < 4; ++j)
            acc[i][j] = __builtin_amdgcn_mfma_f32_16x16x32_bf16(
                af[i], bfr[j], acc[i][j], 0, 0, 0);
        __syncthreads();
      }

#pragma unroll
      for (int j = 0; j < 4; ++j) {
        int cn = n0 + wn + j * 16 + rl;
        float bias = bs[cn];
#pragma unroll
        for (int i = 0; i < 4; ++i) {
#pragma unroll
          for (int r = 0; r < 4; ++r) {
            int gm = m0 + wm + i * 16 + rq + r;
            if (gm < M_MOTIFS) s_out[(size_t)gm * C + cn] = acc[i][j][r] + bias;
          }
        }
      }
    }
  }
}

// ---------------------------------------------------------------------------
// Fallback path (exact R3 kernels) if cooperative launch is unavailable.
// ---------------------------------------------------------------------------
__global__ __launch_bounds__(256) void fill_kernel(
    const int* __restrict__ seg, int* __restrict__ cnt,
    int* __restrict__ nodelist, const float* __restrict__ Ws,
    unsigned short* __restrict__ Wsb) {
  int b = blockIdx.x, t = threadIdx.x;
  if (b < NODE_BLOCKS) {
    int i = b * 256 + t;
    if (i < N_NODES) {
      int m = seg[i];
      int r = atomicAdd(&cnt[m], 1);
      if (r < CAP) nodelist[(size_t)m * CAP + r] = i;
    }
  } else {
    int i = ((b - NODE_BLOCKS) * 256 + t) * 4;
    float4 w = *(const float4*)(Ws + i);
    ushort4 o;
    o.x = f2bf(w.x); o.y = f2bf(w.y); o.z = f2bf(w.z); o.w = f2bf(w.w);
    *(ushort4*)(Wsb + i) = o;
  }
}

__global__ __launch_bounds__(256) void gather_kernel(
    const float* __restrict__ s, const float* __restrict__ v,
    const int* __restrict__ cnt, const int* __restrict__ nodelist,
    const float* __restrict__ Wv, const float* __restrict__ bv,
    unsigned short* __restrict__ s_motif, float* __restrict__ v_out) {
  int m = (blockIdx.x * 256 + threadIdx.x) >> 6;
  int lane = threadIdx.x & 63;
  int k = cnt[m];
  int idv = (k > 0) ? nodelist[(size_t)m * CAP + (lane & 15)] : 0;
  gather_one(m, k, idv, lane, s, v, nodelist, Wv, bv, s_motif, v_out);
}

__global__ __launch_bounds__(256) void gemm_mfma_kernel(
    const unsigned short* __restrict__ A16, const unsigned short* __restrict__ B16,
    const float* __restrict__ bs, float* __restrict__ out) {
  __shared__ unsigned short As[128 * 32];
  __shared__ unsigned short Bs[128 * 32];
  int tid = threadIdx.x;
  int wave = tid >> 6, lane = tid & 63;
  int m0 = blockIdx.x * 128;
  int n0 = blockIdx.y * 128;
  int wm = (wave >> 1) * 64, wn = (wave & 1) * 64;
  f32x4 acc[4][4] = {};
  int srow = lane >> 2;
  int kc = (lane & 3) * 8;
  int rl = lane & 15;
  int kq = (lane >> 4) * 8;
  const unsigned short* Ag = A16 + (size_t)(m0 + wave * 32) * C;
  const unsigned short* Bg = B16 + (size_t)(n0 + wave * 32) * C;
  unsigned short* Al = As + wave * 32 * 32;
  unsigned short* Bl = Bs + wave * 32 * 32;
  for (int k0 = 0; k0 < C; k0 += 32) {
    async_copy16(Ag + (size_t)srow * C + k0 + kc, Al);
    async_copy16(Ag + (size_t)(16 + srow) * C + k0 + kc, Al + 16 * 32);
    async_copy16(Bg + (size_t)srow * C + k0 + kc, Bl);
    async_copy16(Bg + (size_t)(16 + srow) * C + k0 + kc, Bl + 16 * 32);
    __syncthreads();
    bf16x8 af[4], bfr[4];
#pragma unroll
    for (int i = 0; i < 4; ++i)
      af[i] = *(const bf16x8*)&As[(size_t)(wm + i * 16 + rl) * 32 + kq];
#pragma unroll
    for (int j = 0; j < 4; ++j)
      bfr[j] = *(const bf16x8*)&Bs[(size_t)(wn + j * 16 + rl) * 32 + kq];
#pragma unroll
    for (int i = 0; i < 4; ++i)
#pragma unroll
      for (int j = 0; j < 4; ++j)
        acc[i][j] = __builtin_amdgcn_mfma_f32_16x16x32_bf16(
            af[i], bfr[j], acc[i][j], 0, 0, 0);
    __syncthreads();
  }
  int rq = (lane >> 4) * 4;
#pragma unroll
  for (int j = 0; j < 4; ++j) {
    int cn = n0 + wn + j * 16 + rl;
    float bias = bs[cn];
#pragma unroll
    for (int i = 0; i < 4; ++i) {
#pragma unroll
      for (int r = 0; r < 4; ++r) {
        int gm = m0 + wm + i * 16 + rq + r;
        if (gm < M_MOTIFS) out[(size_t)gm * C + cn] = acc[i][j][r] + bias;
      }
    }
  }
}

extern "C" void kernel_launch(void* const* d_in, const int* in_sizes, int n_in,
                              void* d_out, int out_size, void* d_ws, size_t ws_size,
                              hipStream_t stream) {
  const float* s  = (const float*)d_in[0];
  const float* v  = (const float*)d_in[1];
  const int*   seg = (const int*)d_in[2];
  const float* Ws = (const float*)d_in[3];
  const float* bs = (const float*)d_in[4];
  const float* Wv = (const float*)d_in[5];
  const float* bv = (const float*)d_in[6];

  float* out   = (float*)d_out;
  float* s_out = out;
  float* v_out = out + (size_t)M_MOTIFS * C;

  // ws layout (~38.8 MB): [cnt M][nodelist M*CAP][Wsb C*C bf16][s_motif M_PAD*C bf16]
  int* cnt      = (int*)d_ws;
  int* nodelist = cnt + M_MOTIFS;
  unsigned short* Wsb     = (unsigned short*)(nodelist + (size_t)M_MOTIFS * CAP);
  unsigned short* s_motif = Wsb + (size_t)C * C;
  // byte offsets: Wsb = 13,000,000 (16B-aligned); s_motif = 13,131,072 (16B-aligned)

  void* args[] = {(void*)&s, (void*)&v, (void*)&seg, (void*)&Ws, (void*)&bs,
                  (void*)&Wv, (void*)&bv, (void*)&cnt, (void*)&nodelist,
                  (void*)&Wsb, (void*)&s_motif, (void*)&s_out, (void*)&v_out};
  hipError_t err = hipLaunchCooperativeKernel((const void*)mega_kernel,
                                              dim3(CB), dim3(256), args, 0,
                                              stream);
  if (err != hipSuccess) {
    (void)hipGetLastError();   // clear, take the R3 4-dispatch path
    hipMemsetAsync(cnt, 0, M_MOTIFS * sizeof(int), stream);
    fill_kernel<<<NODE_BLOCKS + CVT_BLOCKS, 256, 0, stream>>>(seg, cnt,
                                                              nodelist, Ws, Wsb);
    gather_kernel<<<GATHER_BLOCKS, 256, 0, stream>>>(s, v, cnt, nodelist, Wv,
                                                     bv, s_motif, v_out);
    dim3 grid(M_PAD / 128, C / 128);
    gemm_mfma_kernel<<<grid, 256, 0, stream>>>(s_motif, Wsb, bs, s_out);
  }
}

// Round 8
// 106.542 us; speedup vs baseline: 3.9417x; 3.9417x over previous
//
#include <hip/hip_runtime.h>

#define N_NODES 200000
#define C 256
#define VC 16
#define VD 3
#define VDIM (VC * VD)   // 48
#define M_MOTIFS 50000
#define M_PAD 50048      // padded rows: 50048 = 391 * 128
#define CAP 64           // per-motif slot capacity; Poisson(4) => P(count>64) ~ 1e-36

#define NODE_BLOCKS ((N_NODES + 255) / 256)       // 782
#define CVT_BLOCKS  ((C * C) / (256 * 4))         // 64 (float4 per thread)
#define GATHER_BLOCKS (M_MOTIFS / 4)              // 12500 (4 waves/block, 1 motif/wave)
#define ZERO_BLOCKS ((M_MOTIFS + 255) / 256)      // 196

typedef __attribute__((ext_vector_type(8))) __bf16 bf16x8;
typedef __attribute__((ext_vector_type(4))) float f32x4;

__device__ __forceinline__ unsigned short f2bf(float x) {
  unsigned u = __builtin_bit_cast(unsigned, x);
  u += 0x7fffu + ((u >> 16) & 1u);   // RNE
  return (unsigned short)(u >> 16);
}

// async global->LDS, 16B per lane; LDS dest = wave-uniform base + lane*16
__device__ __forceinline__ void async_copy16(const void* g, void* l) {
  __builtin_amdgcn_global_load_lds(
      (const __attribute__((address_space(1))) unsigned int*)g,
      (__attribute__((address_space(3))) unsigned int*)l, 16, 0, 0);
}

// ---------------------------------------------------------------------------
// K0: zero cnt (replaces hipMemsetAsync's fillBufferAligned node)
// ---------------------------------------------------------------------------
__global__ __launch_bounds__(256) void zero_kernel(int* __restrict__ cnt) {
  int i = blockIdx.x * 256 + threadIdx.x;
  if (i < M_MOTIFS) cnt[i] = 0;
}

// ---------------------------------------------------------------------------
// K1: slot-fill. rank = atomicAdd(cnt[m]); nodelist[m*64+rank] = i.
//     Extra blocks convert Ws->bf16.
// ---------------------------------------------------------------------------
__global__ __launch_bounds__(256) void fill_kernel(
    const int* __restrict__ seg, int* __restrict__ cnt,
    int* __restrict__ nodelist, const float* __restrict__ Ws,
    unsigned short* __restrict__ Wsb) {
  int b = blockIdx.x, t = threadIdx.x;
  if (b < NODE_BLOCKS) {
    int i = b * 256 + t;
    if (i < N_NODES) {
      int m = seg[i];
      int r = atomicAdd(&cnt[m], 1);
      if (r < CAP) nodelist[(size_t)m * CAP + r] = i;
    }
  } else {
    int i = ((b - NODE_BLOCKS) * 256 + t) * 4;
    float4 w = *(const float4*)(Ws + i);
    ushort4 o;
    o.x = f2bf(w.x); o.y = f2bf(w.y); o.z = f2bf(w.z); o.w = f2bf(w.w);
    *(ushort4*)(Wsb + i) = o;
  }
}

// ---------------------------------------------------------------------------
// K2: gather + mean + fused v 16x16 linear. ONE WAVE PER MOTIF (50K waves).
//     R3 body with: (a) idv load hoisted above the k==0 branch (cnt+ids in
//     flight together, branch waits vmcnt(1)); (b) batch-1 issued
//     unconditionally with clamped indices (dups = same-address cache hits)
//     so all 8 row loads + 8 v loads are in flight before any accumulate.
// ---------------------------------------------------------------------------
__global__ __launch_bounds__(256) void gather_kernel(
    const float* __restrict__ s, const float* __restrict__ v,
    const int* __restrict__ cnt, const int* __restrict__ nodelist,
    const float* __restrict__ Wv, const float* __restrict__ bv,
    unsigned short* __restrict__ s_motif, float* __restrict__ v_out) {
  int m = (blockIdx.x * 256 + threadIdx.x) >> 6;   // exact: 12500*4 = 50000
  int lane = threadIdx.x & 63;

  int k = cnt[m];                                       // wave-uniform
  int idv = nodelist[(size_t)m * CAP + (lane & 15)];    // in flight w/ cnt

  if (k == 0) {                                    // ~1.8% of motifs
    ushort4 z; z.x = z.y = z.z = z.w = 0;
    ((ushort4*)(s_motif + (size_t)m * C))[lane] = z;
    if (lane < VDIM) v_out[(size_t)m * VDIM + lane] = bv[lane / 3];
    return;
  }

  int km1 = k - 1;
  int kc = min(k, CAP);

  // ---- all 8 slots clamped, all loads issued before any accumulate ----
  int i0 = __shfl(idv, 0, 64);
  int i1 = __shfl(idv, min(1, km1), 64);
  int i2 = __shfl(idv, min(2, km1), 64);
  int i3 = __shfl(idv, min(3, km1), 64);
  int i4 = __shfl(idv, min(4, km1), 64);
  int i5 = __shfl(idv, min(5, km1), 64);
  int i6 = __shfl(idv, min(6, km1), 64);
  int i7 = __shfl(idv, min(7, km1), 64);
  float4 a0 = ((const float4*)(s + (size_t)i0 * C))[lane];
  float4 a1 = ((const float4*)(s + (size_t)i1 * C))[lane];
  float4 a2 = ((const float4*)(s + (size_t)i2 * C))[lane];
  float4 a3 = ((const float4*)(s + (size_t)i3 * C))[lane];
  float4 a4 = ((const float4*)(s + (size_t)i4 * C))[lane];
  float4 a5 = ((const float4*)(s + (size_t)i5 * C))[lane];
  float4 a6 = ((const float4*)(s + (size_t)i6 * C))[lane];
  float4 a7 = ((const float4*)(s + (size_t)i7 * C))[lane];
  float vb0 = 0.f, vb1 = 0.f, vb2 = 0.f, vb3 = 0.f;
  float vb4 = 0.f, vb5 = 0.f, vb6 = 0.f, vb7 = 0.f;
  if (lane < VDIM) {
    vb0 = v[(size_t)i0 * VDIM + lane];
    vb1 = v[(size_t)i1 * VDIM + lane];
    vb2 = v[(size_t)i2 * VDIM + lane];
    vb3 = v[(size_t)i3 * VDIM + lane];
    vb4 = v[(size_t)i4 * VDIM + lane];
    vb5 = v[(size_t)i5 * VDIM + lane];
    vb6 = v[(size_t)i6 * VDIM + lane];
    vb7 = v[(size_t)i7 * VDIM + lane];
  }
  float4 acc = a0;
  float vacc = vb0;
  if (k > 1) { acc.x += a1.x; acc.y += a1.y; acc.z += a1.z; acc.w += a1.w; vacc += vb1; }
  if (k > 2) { acc.x += a2.x; acc.y += a2.y; acc.z += a2.z; acc.w += a2.w; vacc += vb2; }
  if (k > 3) { acc.x += a3.x; acc.y += a3.y; acc.z += a3.z; acc.w += a3.w; vacc += vb3; }
  if (k > 4) { acc.x += a4.x; acc.y += a4.y; acc.z += a4.z; acc.w += a4.w; vacc += vb4; }
  if (k > 5) { acc.x += a5.x; acc.y += a5.y; acc.z += a5.z; acc.w += a5.w; vacc += vb5; }
  if (k > 6) { acc.x += a6.x; acc.y += a6.y; acc.z += a6.z; acc.w += a6.w; vacc += vb6; }
  if (k > 7) { acc.x += a7.x; acc.y += a7.y; acc.z += a7.z; acc.w += a7.w; vacc += vb7; }

  // ---- rare tail: slots 8.. (2% of motifs)
  if (k > 8) {
    int idv2 = nodelist[(size_t)m * CAP + lane];
    for (int j = 8; j < kc; ++j) {
      int ij = __shfl(idv2, j, 64);
      float4 a = ((const float4*)(s + (size_t)ij * C))[lane];
      acc.x += a.x; acc.y += a.y; acc.z += a.z; acc.w += a.w;
      if (lane < VDIM) vacc += v[(size_t)ij * VDIM + lane];
    }
  }

  float rc = 1.0f / (float)k;
  ushort4 o;
  o.x = f2bf(acc.x * rc); o.y = f2bf(acc.y * rc);
  o.z = f2bf(acc.z * rc); o.w = f2bf(acc.w * rc);
  ((ushort4*)(s_motif + (size_t)m * C))[lane] = o;

  float vm = vacc * rc;   // lane c*3+d holds vmean[c][d]
  if (lane < VDIM) {
    int oo = lane / 3, d = lane - oo * 3;
    float vo = bv[oo];
#pragma unroll
    for (int c2 = 0; c2 < VC; ++c2)
      vo += Wv[oo * VC + c2] * __shfl(vm, c2 * 3 + d, 64);
    v_out[(size_t)m * VDIM + lane] = vo;
  }
}

// ---------------------------------------------------------------------------
// K3: bf16 MFMA GEMM with global_load_lds width=16 staging (R3-verified,
//     UNTOUCHED). 128x128 tile, BK=32, 4 waves (2x2), 4x4 16x16x32 MFMAs.
// ---------------------------------------------------------------------------
__global__ __launch_bounds__(256) void gemm_mfma_kernel(
    const unsigned short* __restrict__ A16,   // s_motif bf16 [M_PAD][256]
    const unsigned short* __restrict__ B16,   // Ws bf16 [256][256]
    const float* __restrict__ bs, float* __restrict__ out) {
  __shared__ unsigned short As[128 * 32];
  __shared__ unsigned short Bs[128 * 32];
  int tid = threadIdx.x;
  int wave = tid >> 6, lane = tid & 63;
  int m0 = blockIdx.x * 128;
  int n0 = blockIdx.y * 128;
  int wm = (wave >> 1) * 64, wn = (wave & 1) * 64;

  f32x4 acc[4][4] = {};

  int srow = lane >> 2;        // 0..15: row within a 16-row staging group
  int kc   = (lane & 3) * 8;   // k element offset (16B chunk)
  int rl = lane & 15;
  int kq = (lane >> 4) * 8;

  const unsigned short* Ag = A16 + (size_t)(m0 + wave * 32) * C;
  const unsigned short* Bg = B16 + (size_t)(n0 + wave * 32) * C;
  unsigned short* Al = As + wave * 32 * 32;
  unsigned short* Bl = Bs + wave * 32 * 32;

  for (int k0 = 0; k0 < C; k0 += 32) {
    async_copy16(Ag + (size_t)srow * C + k0 + kc, Al);
    async_copy16(Ag + (size_t)(16 + srow) * C + k0 + kc, Al + 16 * 32);
    async_copy16(Bg + (size_t)srow * C + k0 + kc, Bl);
    async_copy16(Bg + (size_t)(16 + srow) * C + k0 + kc, Bl + 16 * 32);
    __syncthreads();

    bf16x8 af[4], bfr[4];
#pragma unroll
    for (int i = 0; i < 4; ++i)
      af[i] = *(const bf16x8*)&As[(size_t)(wm + i * 16 + rl) * 32 + kq];
#pragma unroll
    for (int j = 0; j < 4; ++j)
      bfr[j] = *(const bf16x8*)&Bs[(size_t)(wn + j * 16 + rl) * 32 + kq];
#pragma unroll
    for (int i = 0; i < 4; ++i)
#pragma unroll
      for (int j = 0; j < 4; ++j)
        acc[i][j] = __builtin_amdgcn_mfma_f32_16x16x32_bf16(
            af[i], bfr[j], acc[i][j], 0, 0, 0);
    __syncthreads();
  }

  int rq = (lane >> 4) * 4;
#pragma unroll
  for (int j = 0; j < 4; ++j) {
    int cn = n0 + wn + j * 16 + rl;
    float bias = bs[cn];
#pragma unroll
    for (int i = 0; i < 4; ++i) {
#pragma unroll
      for (int r = 0; r < 4; ++r) {
        int gm = m0 + wm + i * 16 + rq + r;
        if (gm < M_MOTIFS) out[(size_t)gm * C + cn] = acc[i][j][r] + bias;
      }
    }
  }
}

extern "C" void kernel_launch(void* const* d_in, const int* in_sizes, int n_in,
                              void* d_out, int out_size, void* d_ws, size_t ws_size,
                              hipStream_t stream) {
  const float* s  = (const float*)d_in[0];
  const float* v  = (const float*)d_in[1];
  const int*   seg = (const int*)d_in[2];
  const float* Ws = (const float*)d_in[3];
  const float* bs = (const float*)d_in[4];
  const float* Wv = (const float*)d_in[5];
  const float* bv = (const float*)d_in[6];

  float* out   = (float*)d_out;
  float* s_out = out;
  float* v_out = out + (size_t)M_MOTIFS * C;

  // ws layout (~38.8 MB): [cnt M][nodelist M*CAP][Wsb C*C bf16][s_motif M_PAD*C bf16]
  int* cnt      = (int*)d_ws;
  int* nodelist = cnt + M_MOTIFS;
  unsigned short* Wsb     = (unsigned short*)(nodelist + (size_t)M_MOTIFS * CAP);
  unsigned short* s_motif = Wsb + (size_t)C * C;

  zero_kernel<<<ZERO_BLOCKS, 256, 0, stream>>>(cnt);
  fill_kernel<<<NODE_BLOCKS + CVT_BLOCKS, 256, 0, stream>>>(seg, cnt, nodelist,
                                                            Ws, Wsb);
  gather_kernel<<<GATHER_BLOCKS, 256, 0, stream>>>(s, v, cnt, nodelist, Wv, bv,
                                                   s_motif, v_out);
  {
    dim3 grid(M_PAD / 128, C / 128);   // 391 x 2
    gemm_mfma_kernel<<<grid, 256, 0, stream>>>(s_motif, Wsb, bs, s_out);
  }
}

// Round 9
// 104.099 us; speedup vs baseline: 4.0343x; 1.0235x over previous
//
#include <hip/hip_runtime.h>

#define N_NODES 200000
#define C 256
#define VC 16
#define VD 3
#define VDIM (VC * VD)   // 48
#define M_MOTIFS 50000
#define M_PAD 50048      // padded rows: 50048 = 391 * 128
#define CAP 64           // per-motif slot capacity; Poisson(4) => P(count>64) ~ 1e-36

#define NODE_BLOCKS ((N_NODES + 255) / 256)       // 782
#define CVT_BLOCKS  ((C * C) / (256 * 4))         // 64 (float4 per thread)
#define GATHER_BLOCKS (M_MOTIFS / 4)              // 12500 (4 waves/block, 1 motif/wave)

typedef __attribute__((ext_vector_type(8))) __bf16 bf16x8;
typedef __attribute__((ext_vector_type(4))) float f32x4;

__device__ __forceinline__ unsigned short f2bf(float x) {
  unsigned u = __builtin_bit_cast(unsigned, x);
  u += 0x7fffu + ((u >> 16) & 1u);   // RNE
  return (unsigned short)(u >> 16);
}

// async global->LDS, 16B per lane; LDS dest = wave-uniform base + lane*16
__device__ __forceinline__ void async_copy16(const void* g, void* l) {
  __builtin_amdgcn_global_load_lds(
      (const __attribute__((address_space(1))) unsigned int*)g,
      (__attribute__((address_space(3))) unsigned int*)l, 16, 0, 0);
}

// ---------------------------------------------------------------------------
// K1: slot-fill. rank = atomicAdd(cnt[m]); nodelist[m*64+rank] = i.
//     Extra blocks convert Ws->bf16.
// ---------------------------------------------------------------------------
__global__ __launch_bounds__(256) void fill_kernel(
    const int* __restrict__ seg, int* __restrict__ cnt,
    int* __restrict__ nodelist, const float* __restrict__ Ws,
    unsigned short* __restrict__ Wsb) {
  int b = blockIdx.x, t = threadIdx.x;
  if (b < NODE_BLOCKS) {
    int i = b * 256 + t;
    if (i < N_NODES) {
      int m = seg[i];
      int r = atomicAdd(&cnt[m], 1);
      if (r < CAP) nodelist[(size_t)m * CAP + r] = i;
    }
  } else {
    int i = ((b - NODE_BLOCKS) * 256 + t) * 4;
    float4 w = *(const float4*)(Ws + i);
    ushort4 o;
    o.x = f2bf(w.x); o.y = f2bf(w.y); o.z = f2bf(w.z); o.w = f2bf(w.w);
    *(ushort4*)(Wsb + i) = o;
  }
}

// ---------------------------------------------------------------------------
// K2: gather + mean + fused v 16x16 linear. ONE WAVE PER MOTIF (50K waves).
//     EXACT R3 body (measured best, 104.1 us total) with ONE delta: the idv
//     slot-id load is hoisted above the k==0 branch so both metadata loads
//     are in flight together (branch waits vmcnt(1) on cnt only). Adds no
//     loads, removes one dependent HBM round trip from the critical path.
// ---------------------------------------------------------------------------
__global__ __launch_bounds__(256) void gather_kernel(
    const float* __restrict__ s, const float* __restrict__ v,
    const int* __restrict__ cnt, const int* __restrict__ nodelist,
    const float* __restrict__ Wv, const float* __restrict__ bv,
    unsigned short* __restrict__ s_motif, float* __restrict__ v_out) {
  int m = (blockIdx.x * 256 + threadIdx.x) >> 6;   // exact: 12500*4 = 50000
  int lane = threadIdx.x & 63;

  int k = cnt[m];                                       // wave-uniform
  int idv = nodelist[(size_t)m * CAP + (lane & 15)];    // in flight w/ cnt

  if (k == 0) {                                    // ~1.8% of motifs
    ushort4 z; z.x = z.y = z.z = z.w = 0;
    ((ushort4*)(s_motif + (size_t)m * C))[lane] = z;
    if (lane < VDIM) v_out[(size_t)m * VDIM + lane] = bv[lane / 3];
    return;
  }

  int km1 = k - 1;
  int kc = min(k, CAP);

  // ---- batch 0: slots 0..3 (clamped; duplicates are same-address L1 hits)
  int i0 = __shfl(idv, 0, 64);
  int i1 = __shfl(idv, min(1, km1), 64);
  int i2 = __shfl(idv, min(2, km1), 64);
  int i3 = __shfl(idv, min(3, km1), 64);
  float4 a0 = ((const float4*)(s + (size_t)i0 * C))[lane];
  float4 a1 = ((const float4*)(s + (size_t)i1 * C))[lane];
  float4 a2 = ((const float4*)(s + (size_t)i2 * C))[lane];
  float4 a3 = ((const float4*)(s + (size_t)i3 * C))[lane];
  float vb0 = 0.f, vb1 = 0.f, vb2 = 0.f, vb3 = 0.f;
  if (lane < VDIM) {
    vb0 = v[(size_t)i0 * VDIM + lane];
    vb1 = v[(size_t)i1 * VDIM + lane];
    vb2 = v[(size_t)i2 * VDIM + lane];
    vb3 = v[(size_t)i3 * VDIM + lane];
  }
  float4 acc = a0;
  float vacc = vb0;
  if (k > 1) { acc.x += a1.x; acc.y += a1.y; acc.z += a1.z; acc.w += a1.w; vacc += vb1; }
  if (k > 2) { acc.x += a2.x; acc.y += a2.y; acc.z += a2.z; acc.w += a2.w; vacc += vb2; }
  if (k > 3) { acc.x += a3.x; acc.y += a3.y; acc.z += a3.z; acc.w += a3.w; vacc += vb3; }

  // ---- batch 1: slots 4..7 (37% of motifs)
  if (k > 4) {
    int i4 = __shfl(idv, min(4, km1), 64);
    int i5 = __shfl(idv, min(5, km1), 64);
    int i6 = __shfl(idv, min(6, km1), 64);
    int i7 = __shfl(idv, min(7, km1), 64);
    float4 b4 = ((const float4*)(s + (size_t)i4 * C))[lane];
    float4 b5 = ((const float4*)(s + (size_t)i5 * C))[lane];
    float4 b6 = ((const float4*)(s + (size_t)i6 * C))[lane];
    float4 b7 = ((const float4*)(s + (size_t)i7 * C))[lane];
    float w4 = 0.f, w5 = 0.f, w6 = 0.f, w7 = 0.f;
    if (lane < VDIM) {
      w4 = v[(size_t)i4 * VDIM + lane];
      w5 = v[(size_t)i5 * VDIM + lane];
      w6 = v[(size_t)i6 * VDIM + lane];
      w7 = v[(size_t)i7 * VDIM + lane];
    }
    acc.x += b4.x; acc.y += b4.y; acc.z += b4.z; acc.w += b4.w; vacc += w4;
    if (k > 5) { acc.x += b5.x; acc.y += b5.y; acc.z += b5.z; acc.w += b5.w; vacc += w5; }
    if (k > 6) { acc.x += b6.x; acc.y += b6.y; acc.z += b6.z; acc.w += b6.w; vacc += w6; }
    if (k > 7) { acc.x += b7.x; acc.y += b7.y; acc.z += b7.z; acc.w += b7.w; vacc += w7; }
  }

  // ---- rare tail: slots 8.. (2% of motifs)
  if (k > 8) {
    int idv2 = nodelist[(size_t)m * CAP + lane];
    for (int j = 8; j < kc; ++j) {
      int ij = __shfl(idv2, j, 64);
      float4 a = ((const float4*)(s + (size_t)ij * C))[lane];
      acc.x += a.x; acc.y += a.y; acc.z += a.z; acc.w += a.w;
      if (lane < VDIM) vacc += v[(size_t)ij * VDIM + lane];
    }
  }

  float rc = 1.0f / (float)k;
  ushort4 o;
  o.x = f2bf(acc.x * rc); o.y = f2bf(acc.y * rc);
  o.z = f2bf(acc.z * rc); o.w = f2bf(acc.w * rc);
  ((ushort4*)(s_motif + (size_t)m * C))[lane] = o;

  float vm = vacc * rc;   // lane c*3+d holds vmean[c][d]
  if (lane < VDIM) {
    int oo = lane / 3, d = lane - oo * 3;
    float vo = bv[oo];
#pragma unroll
    for (int c2 = 0; c2 < VC; ++c2)
      vo += Wv[oo * VC + c2] * __shfl(vm, c2 * 3 + d, 64);
    v_out[(size_t)m * VDIM + lane] = vo;
  }
}

// ---------------------------------------------------------------------------
// K3: bf16 MFMA GEMM with global_load_lds width=16 staging (R3-verified,
//     UNTOUCHED). 128x128 tile, BK=32, 4 waves (2x2), 4x4 16x16x32 MFMAs.
// ---------------------------------------------------------------------------
__global__ __launch_bounds__(256) void gemm_mfma_kernel(
    const unsigned short* __restrict__ A16,   // s_motif bf16 [M_PAD][256]
    const unsigned short* __restrict__ B16,   // Ws bf16 [256][256]
    const float* __restrict__ bs, float* __restrict__ out) {
  __shared__ unsigned short As[128 * 32];
  __shared__ unsigned short Bs[128 * 32];
  int tid = threadIdx.x;
  int wave = tid >> 6, lane = tid & 63;
  int m0 = blockIdx.x * 128;
  int n0 = blockIdx.y * 128;
  int wm = (wave >> 1) * 64, wn = (wave & 1) * 64;

  f32x4 acc[4][4] = {};

  int srow = lane >> 2;        // 0..15: row within a 16-row staging group
  int kc   = (lane & 3) * 8;   // k element offset (16B chunk)
  int rl = lane & 15;
  int kq = (lane >> 4) * 8;

  const unsigned short* Ag = A16 + (size_t)(m0 + wave * 32) * C;
  const unsigned short* Bg = B16 + (size_t)(n0 + wave * 32) * C;
  unsigned short* Al = As + wave * 32 * 32;
  unsigned short* Bl = Bs + wave * 32 * 32;

  for (int k0 = 0; k0 < C; k0 += 32) {
    async_copy16(Ag + (size_t)srow * C + k0 + kc, Al);
    async_copy16(Ag + (size_t)(16 + srow) * C + k0 + kc, Al + 16 * 32);
    async_copy16(Bg + (size_t)srow * C + k0 + kc, Bl);
    async_copy16(Bg + (size_t)(16 + srow) * C + k0 + kc, Bl + 16 * 32);
    __syncthreads();

    bf16x8 af[4], bfr[4];
#pragma unroll
    for (int i = 0; i < 4; ++i)
      af[i] = *(const bf16x8*)&As[(size_t)(wm + i * 16 + rl) * 32 + kq];
#pragma unroll
    for (int j = 0; j < 4; ++j)
      bfr[j] = *(const bf16x8*)&Bs[(size_t)(wn + j * 16 + rl) * 32 + kq];
#pragma unroll
    for (int i = 0; i < 4; ++i)
#pragma unroll
      for (int j = 0; j < 4; ++j)
        acc[i][j] = __builtin_amdgcn_mfma_f32_16x16x32_bf16(
            af[i], bfr[j], acc[i][j], 0, 0, 0);
    __syncthreads();
  }

  int rq = (lane >> 4) * 4;
#pragma unroll
  for (int j = 0; j < 4; ++j) {
    int cn = n0 + wn + j * 16 + rl;
    float bias = bs[cn];
#pragma unroll
    for (int i = 0; i < 4; ++i) {
#pragma unroll
      for (int r = 0; r < 4; ++r) {
        int gm = m0 + wm + i * 16 + rq + r;
        if (gm < M_MOTIFS) out[(size_t)gm * C + cn] = acc[i][j][r] + bias;
      }
    }
  }
}

extern "C" void kernel_launch(void* const* d_in, const int* in_sizes, int n_in,
                              void* d_out, int out_size, void* d_ws, size_t ws_size,
                              hipStream_t stream) {
  const float* s  = (const float*)d_in[0];
  const float* v  = (const float*)d_in[1];
  const int*   seg = (const int*)d_in[2];
  const float* Ws = (const float*)d_in[3];
  const float* bs = (const float*)d_in[4];
  const float* Wv = (const float*)d_in[5];
  const float* bv = (const float*)d_in[6];

  float* out   = (float*)d_out;
  float* s_out = out;
  float* v_out = out + (size_t)M_MOTIFS * C;

  // ws layout (~38.8 MB): [cnt M][nodelist M*CAP][Wsb C*C bf16][s_motif M_PAD*C bf16]
  int* cnt      = (int*)d_ws;
  int* nodelist = cnt + M_MOTIFS;
  unsigned short* Wsb     = (unsigned short*)(nodelist + (size_t)M_MOTIFS * CAP);
  unsigned short* s_motif = Wsb + (size_t)C * C;

  hipMemsetAsync(cnt, 0, M_MOTIFS * sizeof(int), stream);
  fill_kernel<<<NODE_BLOCKS + CVT_BLOCKS, 256, 0, stream>>>(seg, cnt, nodelist,
                                                            Ws, Wsb);
  gather_kernel<<<GATHER_BLOCKS, 256, 0, stream>>>(s, v, cnt, nodelist, Wv, bv,
                                                   s_motif, v_out);
  {
    dim3 grid(M_PAD / 128, C / 128);   // 391 x 2
    gemm_mfma_kernel<<<grid, 256, 0, stream>>>(s_motif, Wsb, bs, s_out);
  }
}